// Round 2
// baseline (481.112 us; speedup 1.0000x reference)
//
#include <hip/hip_runtime.h>
#include <cstdint>
#include <cstddef>

#define NN 50000
#define NE 200000
#define IND 768
#define HID 256
#define OUTD 64
#define NB 196  // ceil(NN/256)

typedef __bf16 bf16;
typedef __bf16 bf16x8 __attribute__((ext_vector_type(8)));
typedef float f32x4 __attribute__((ext_vector_type(4)));

// ---------------- edge prep: last-write-wins scatter index + dst histogram ----------------
__global__ __launch_bounds__(256) void k_edge_prep(const int* __restrict__ ei,
                                                   int* __restrict__ le, int* __restrict__ deg) {
  int e = blockIdx.x * 256 + threadIdx.x;
  if (e < NE) {
    atomicMax(&le[ei[e]], e);        // src: last edge index wins
    atomicAdd(&deg[ei[NE + e]], 1);  // dst degree
  }
}

// eembz: [R+1][IND], rows 0..5 = eemb, row 6 = zeros (branchless "no edge" row)
__global__ __launch_bounds__(256) void k_eembz(const float* __restrict__ eemb,
                                               float* __restrict__ ez) {
  int i = blockIdx.x * 256 + threadIdx.x;
  if (i < 7 * IND) ez[i] = (i < 6 * IND) ? eemb[i] : 0.f;
}

// ---------------- A1 = bf16(x + eembz[et[le[row]]]) : pure streaming prepass ----------------
// Decouples the fuse from the GEMM so the GEMM can use the proven
// global_load_lds structure (reg-staged fuse caps it — see m93 vs m97).
__global__ __launch_bounds__(256) void k_prep_a(const float* __restrict__ x,
                                                const int* __restrict__ le,
                                                const int* __restrict__ et,
                                                const float* __restrict__ eembz,
                                                bf16* __restrict__ A1) {
  int idx = blockIdx.x * 256 + threadIdx.x;  // one thread = 8 elements
  if (idx >= NN * (IND / 8)) return;
  int row = idx / (IND / 8);
  int c = (idx - row * (IND / 8)) * 8;
  int l = le[row];
  int e = (l >= 0) ? et[l] : 6;  // row 6 of eembz is zeros
  const float* px = x + (size_t)row * IND + c;
  const float* pe = eembz + (size_t)e * IND + c;
  float4 v0 = *(const float4*)px, v1 = *(const float4*)(px + 4);
  float4 e0 = *(const float4*)pe, e1 = *(const float4*)(pe + 4);
  bf16x8 o;
  o[0] = (bf16)(v0.x + e0.x); o[1] = (bf16)(v0.y + e0.y);
  o[2] = (bf16)(v0.z + e0.z); o[3] = (bf16)(v0.w + e0.w);
  o[4] = (bf16)(v1.x + e1.x); o[5] = (bf16)(v1.y + e1.y);
  o[6] = (bf16)(v1.z + e1.z); o[7] = (bf16)(v1.w + e1.w);
  *(bf16x8*)(A1 + (size_t)row * IND + c) = o;
}

// ---------------- CSR build: scan + scatter ----------------
__global__ __launch_bounds__(256) void k_scan_block(const int* __restrict__ deg,
                                                    int* __restrict__ excl, int* __restrict__ bsum) {
  __shared__ int sm[256];
  int tid = threadIdx.x;
  int i = blockIdx.x * 256 + tid;
  int v = (i < NN) ? deg[i] : 0;
  sm[tid] = v;
  __syncthreads();
#pragma unroll
  for (int off = 1; off < 256; off <<= 1) {
    int t = (tid >= off) ? sm[tid - off] : 0;
    __syncthreads();
    sm[tid] += t;
    __syncthreads();
  }
  if (i < NN) excl[i] = sm[tid] - v;
  if (tid == 255) bsum[blockIdx.x] = sm[255];
}

__global__ __launch_bounds__(256) void k_scan_partials(const int* __restrict__ bsum,
                                                       int* __restrict__ bbase) {
  __shared__ int sm[256];
  int tid = threadIdx.x;
  int v = (tid < NB) ? bsum[tid] : 0;
  sm[tid] = v;
  __syncthreads();
#pragma unroll
  for (int off = 1; off < 256; off <<= 1) {
    int t = (tid >= off) ? sm[tid - off] : 0;
    __syncthreads();
    sm[tid] += t;
    __syncthreads();
  }
  bbase[tid] = sm[tid] - v;
}

__global__ __launch_bounds__(256) void k_add_base(const int* __restrict__ excl,
                                                  const int* __restrict__ bbase,
                                                  int* __restrict__ rowstart, int* __restrict__ cur) {
  int i = blockIdx.x * 256 + threadIdx.x;
  if (i < NN) {
    int rs = excl[i] + bbase[i >> 8];
    rowstart[i] = rs;
    cur[i] = rs;
  }
}

__global__ __launch_bounds__(256) void k_scatter_csr(const int* __restrict__ ei,
                                                     int* __restrict__ cur, int* __restrict__ csr) {
  int e = blockIdx.x * 256 + threadIdx.x;
  if (e < NE) {
    int d = ei[NE + e];
    int pos = atomicAdd(&cur[d], 1);
    csr[pos] = ei[e];  // store src node id
  }
}

// W [K, NC] fp32 -> Wt [NC, K] bf16
__global__ __launch_bounds__(256) void k_transpose(const float* __restrict__ W,
                                                   bf16* __restrict__ Wt, int K, int NC) {
  int k = blockIdx.x * 256 + threadIdx.x;
  int n = blockIdx.y;
  if (k < K) Wt[n * K + k] = (bf16)W[k * NC + n];
}

__device__ __forceinline__ void gld16(const bf16* g, bf16* l) {
  __builtin_amdgcn_global_load_lds((const __attribute__((address_space(1))) void*)g,
                                   (__attribute__((address_space(3))) void*)l, 16, 0, 0);
}

// ---------------- MFMA GEMM: C[M,NC] = A[M,K] * Bt[NC,K]^T ----------------
// m97 structure: 128x128 tile, BK=32, 4 waves 2x2, 16 MFMA/wave/K-step,
// global_load_lds width-16 staging (linear LDS dest = wave-uniform base +
// lane*16; per-lane global src), single-buffer 2-barrier loop.
// Epilogue emits attention logits alS/alD (per-row dot with aS/aD):
// each wave's 64-col slice == one head slice -> plain stores, no atomics.
template <typename OutT>
__global__ __launch_bounds__(256) void k_gemm_bt(const bf16* __restrict__ A,
                                                 const bf16* __restrict__ Bt,
                                                 OutT* __restrict__ C,
                                                 int M, int K, int NC,
                                                 const float* __restrict__ aS,
                                                 const float* __restrict__ aD,
                                                 float* __restrict__ alS,
                                                 float* __restrict__ alD,
                                                 int alStride) {
  __shared__ bf16 As[128 * 32];
  __shared__ bf16 Bs[128 * 32];
  const int tid = threadIdx.x;
  const int lane = tid & 63;
  const int wave = tid >> 6;
  const int wr = wave >> 1, wc = wave & 1;
  const int ln15 = lane & 15, q = lane >> 4;
  const int n0 = blockIdx.x * 128;  // n fastest-varying: adjacent blocks share A-tile
  const int m0 = blockIdx.y * 128;

  // staging: wave stages rows [wave*32, wave*32+32) of As and Bs as two 1KB calls.
  // lane l -> row +(l>>2), 16B chunk (l&3) of the 64B row (matches [row][32] layout).
  const int sr = lane >> 2;
  const int scol = (lane & 3) * 8;  // bf16 elements
  const int gA0 = min(m0 + wave * 32 + sr, M - 1);
  const int gA1 = min(m0 + wave * 32 + 16 + sr, M - 1);
  const int gB0 = min(n0 + wave * 32 + sr, NC - 1);
  const int gB1 = min(n0 + wave * 32 + 16 + sr, NC - 1);
  bf16* lA0 = As + (wave * 32) * 32;       // wave-uniform LDS bases
  bf16* lA1 = As + (wave * 32 + 16) * 32;
  bf16* lB0 = Bs + (wave * 32) * 32;
  bf16* lB1 = Bs + (wave * 32 + 16) * 32;

  f32x4 acc[4][4] = {};

  for (int kt = 0; kt < K; kt += 32) {
    gld16(A + (size_t)gA0 * K + kt + scol, lA0);
    gld16(A + (size_t)gA1 * K + kt + scol, lA1);
    gld16(Bt + (size_t)gB0 * K + kt + scol, lB0);
    gld16(Bt + (size_t)gB1 * K + kt + scol, lB1);
    __syncthreads();  // vmcnt(0) drain + publish
    bf16x8 af[4], bfr[4];
#pragma unroll
    for (int i = 0; i < 4; i++)
      af[i] = *(const bf16x8*)(As + (wr * 64 + i * 16 + ln15) * 32 + q * 8);
#pragma unroll
    for (int i = 0; i < 4; i++)
      bfr[i] = *(const bf16x8*)(Bs + (wc * 64 + i * 16 + ln15) * 32 + q * 8);
#pragma unroll
    for (int mi = 0; mi < 4; mi++)
#pragma unroll
      for (int ni = 0; ni < 4; ni++)
        acc[mi][ni] = __builtin_amdgcn_mfma_f32_16x16x32_bf16(af[mi], bfr[ni], acc[mi][ni], 0, 0, 0);
    __syncthreads();  // WAR: protect LDS before next stage
  }

  // epilogue 1: C store. C/D layout col=lane&15, row=(lane>>4)*4+reg
#pragma unroll
  for (int mi = 0; mi < 4; mi++)
#pragma unroll
    for (int ni = 0; ni < 4; ni++)
#pragma unroll
      for (int r = 0; r < 4; r++) {
        int row = m0 + wr * 64 + mi * 16 + q * 4 + r;
        int col = n0 + wc * 64 + ni * 16 + ln15;
        if (row < M && col < NC) C[(size_t)row * NC + col] = (OutT)acc[mi][ni][r];
      }

  // epilogue 2: attention logits
  if (n0 + wc * 64 < NC) {
    const int hd = (n0 + wc * 64) >> 6;
#pragma unroll
    for (int mi = 0; mi < 4; mi++)
#pragma unroll
      for (int r = 0; r < 4; r++) {
        float ps = 0.f, pd = 0.f;
#pragma unroll
        for (int ni = 0; ni < 4; ni++) {
          int col = n0 + wc * 64 + ni * 16 + ln15;
          float w_s = (col < NC) ? aS[col] : 0.f;
          float w_d = (col < NC) ? aD[col] : 0.f;
          ps += acc[mi][ni][r] * w_s;
          pd += acc[mi][ni][r] * w_d;
        }
#pragma unroll
        for (int off = 1; off < 16; off <<= 1) {
          ps += __shfl_xor(ps, off);
          pd += __shfl_xor(pd, off);
        }
        int row = m0 + wr * 64 + mi * 16 + q * 4 + r;
        if (ln15 == 0 && row < M) {
          alS[row * alStride + hd] = ps;
          alD[row * alStride + hd] = pd;
        }
      }
  }
}

// ---------------- fused gather-aggregate + LN + ELU, layer 1 ----------------
__global__ __launch_bounds__(256) void k_agg_ln1(const int* __restrict__ rowstart,
                                                 const int* __restrict__ deg,
                                                 const int* __restrict__ csr,
                                                 const bf16* __restrict__ h1,
                                                 const float* __restrict__ alS,
                                                 const float* __restrict__ alD,
                                                 const float* __restrict__ b1,
                                                 const float* __restrict__ g1,
                                                 const float* __restrict__ be1,
                                                 bf16* __restrict__ hln) {
  __shared__ float red[8];
  int n = blockIdx.x, f = threadIdx.x, hd = f >> 6;
  int start = rowstart[n], cnt = deg[n];
  float ald = alD[n * 4 + hd];
  float accv = 0.f, accw = 0.f;
  for (int j = 0; j < cnt; j++) {
    int s = csr[start + j];
    float logit = alS[s * 4 + hd] + ald;
    logit = logit >= 0.f ? logit : 0.2f * logit;
    float w = __expf(logit);  // shift-free softmax: logits bounded by construction
    accv += w * (float)h1[(size_t)s * HID + f];
    accw += w;
  }
  float v = (cnt > 0) ? accv / accw : 0.f;
  v += b1[f];
  float s = v, ss = v * v;
#pragma unroll
  for (int off = 32; off; off >>= 1) { s += __shfl_xor(s, off); ss += __shfl_xor(ss, off); }
  if ((f & 63) == 0) { red[f >> 6] = s; red[4 + (f >> 6)] = ss; }
  __syncthreads();
  float tot = red[0] + red[1] + red[2] + red[3];
  float tss = red[4] + red[5] + red[6] + red[7];
  float mu = tot * (1.f / HID);
  float var = tss * (1.f / HID) - mu * mu;
  float y = (v - mu) * rsqrtf(var + 1e-5f) * g1[f] + be1[f];
  y = y > 0.f ? y : __expf(y) - 1.f;  // ELU
  hln[(size_t)n * HID + f] = (bf16)y;
}

// ---------------- fused gather-aggregate + LN, layer 2 ----------------
__global__ __launch_bounds__(64) void k_agg_ln2(const int* __restrict__ rowstart,
                                                const int* __restrict__ deg,
                                                const int* __restrict__ csr,
                                                const float* __restrict__ h2,
                                                const float* __restrict__ alS,
                                                const float* __restrict__ alD,
                                                const float* __restrict__ b2,
                                                const float* __restrict__ g2,
                                                const float* __restrict__ be2,
                                                float* __restrict__ out) {
  int n = blockIdx.x, f = threadIdx.x;
  int start = rowstart[n], cnt = deg[n];
  float ald = alD[n];
  float accv = 0.f, accw = 0.f;
  for (int j = 0; j < cnt; j++) {
    int s = csr[start + j];
    float logit = alS[s] + ald;
    logit = logit >= 0.f ? logit : 0.2f * logit;
    float w = __expf(logit);
    accv += w * h2[(size_t)s * OUTD + f];
    accw += w;
  }
  float v = (cnt > 0) ? accv / accw : 0.f;
  v += b2[f];
  float s = v, ss = v * v;
#pragma unroll
  for (int off = 32; off; off >>= 1) { s += __shfl_xor(s, off); ss += __shfl_xor(ss, off); }
  float mu = s * (1.f / OUTD);
  float var = ss * (1.f / OUTD) - mu * mu;
  out[(size_t)n * OUTD + f] = (v - mu) * rsqrtf(var + 1e-5f) * g2[f] + be2[f];
}

extern "C" void kernel_launch(void* const* d_in, const int* in_sizes, int n_in,
                              void* d_out, int out_size, void* d_ws, size_t ws_size,
                              hipStream_t stream) {
  const float* x    = (const float*)d_in[0];
  const int*   ei   = (const int*)d_in[1];
  const int*   et   = (const int*)d_in[2];
  const float* eemb = (const float*)d_in[3];
  const float* W1   = (const float*)d_in[4];
  const float* as1  = (const float*)d_in[5];
  const float* ad1  = (const float*)d_in[6];
  const float* b1   = (const float*)d_in[7];
  const float* g1   = (const float*)d_in[8];
  const float* be1  = (const float*)d_in[9];
  const float* W2   = (const float*)d_in[10];
  const float* as2  = (const float*)d_in[11];
  const float* ad2  = (const float*)d_in[12];
  const float* b2   = (const float*)d_in[13];
  const float* g2   = (const float*)d_in[14];
  const float* be2  = (const float*)d_in[15];
  float* out = (float*)d_out;

  char* base = (char*)d_ws;
  size_t off = 0;
  auto alloc = [&](size_t bytes) -> void* {
    void* p = base + off;
    off = (off + bytes + 255) & ~(size_t)255;
    return p;
  };
  int*   le    = (int*)alloc((size_t)NN * 4);
  int*   deg   = (int*)alloc((size_t)NN * 4);
  int*   excl  = (int*)alloc((size_t)NN * 4);
  int*   bsum  = (int*)alloc(256 * 4);
  int*   bbase = (int*)alloc(256 * 4);
  int*   rowst = (int*)alloc((size_t)NN * 4);
  int*   cur   = (int*)alloc((size_t)NN * 4);
  int*   csr   = (int*)alloc((size_t)NE * 4);
  bf16*  h1    = (bf16*)alloc((size_t)NN * HID * 2);
  float* alS1  = (float*)alloc((size_t)NN * 4 * 4);
  float* alD1  = (float*)alloc((size_t)NN * 4 * 4);
  bf16*  W1t   = (bf16*)alloc((size_t)HID * IND * 2);
  bf16*  W2t   = (bf16*)alloc((size_t)OUTD * HID * 2);
  float* eembz = (float*)alloc((size_t)7 * IND * 4);
  // region R: A1 (live prep_a..gemm1) aliased by {hln, h2, alS2, alD2} (live after gemm1)
  char*  R     = (char*)alloc((size_t)NN * IND * 2);
  bf16*  A1    = (bf16*)R;
  bf16*  hln   = (bf16*)R;
  float* h2    = (float*)(R + (size_t)NN * HID * 2);
  float* alS2  = (float*)(R + (size_t)NN * HID * 2 + (size_t)NN * OUTD * 4);
  float* alD2  = (float*)(R + (size_t)NN * HID * 2 + (size_t)NN * OUTD * 4 + (size_t)NN * 4);

  hipMemsetAsync(le, 0xFF, (size_t)NN * 4, stream);  // -1
  hipMemsetAsync(deg, 0, (size_t)NN * 4, stream);

  // CSR build + last-edge index + zero-padded edge-emb table
  k_edge_prep<<<(NE + 255) / 256, 256, 0, stream>>>(ei, le, deg);
  k_eembz<<<(7 * IND + 255) / 256, 256, 0, stream>>>(eemb, eembz);
  // streaming prepass: A1 = bf16(x + edge_emb)
  k_prep_a<<<(NN * (IND / 8) + 255) / 256, 256, 0, stream>>>(x, le, et, eembz, A1);
  k_scan_block<<<NB, 256, 0, stream>>>(deg, excl, bsum);
  k_scan_partials<<<1, 256, 0, stream>>>(bsum, bbase);
  k_add_base<<<NB, 256, 0, stream>>>(excl, bbase, rowst, cur);
  k_scatter_csr<<<(NE + 255) / 256, 256, 0, stream>>>(ei, cur, csr);

  // weights
  k_transpose<<<dim3(3, HID), 256, 0, stream>>>(W1, W1t, IND, HID);
  k_transpose<<<dim3(1, OUTD), 256, 0, stream>>>(W2, W2t, HID, OUTD);

  // layer 1: clean bf16 GEMM -> h1 + logits
  k_gemm_bt<bf16><<<dim3(2, (NN + 127) / 128), 256, 0, stream>>>(
      A1, W1t, h1, NN, IND, HID, as1, ad1, alS1, alD1, 4);
  k_agg_ln1<<<NN, 256, 0, stream>>>(rowst, deg, csr, h1, alS1, alD1, b1, g1, be1, hln);

  // layer 2: GEMM -> h2 + logits
  k_gemm_bt<float><<<dim3(1, (NN + 127) / 128), 256, 0, stream>>>(
      hln, W2t, h2, NN, HID, OUTD, as2, ad2, alS2, alD2, 1);
  k_agg_ln2<<<NN, 64, 0, stream>>>(rowst, deg, csr, h2, alS2, alD2, b2, g2, be2, out);
}

// Round 3
// 437.997 us; speedup vs baseline: 1.0984x; 1.0984x over previous
//
#include <hip/hip_runtime.h>
#include <cstdint>
#include <cstddef>

#define NN 50000
#define NE 200000
#define IND 768
#define HID 256
#define OUTD 64
#define NB 196  // ceil(NN/256)

typedef __bf16 bf16;
typedef __bf16 bf16x8 __attribute__((ext_vector_type(8)));
typedef __bf16 bf16x4 __attribute__((ext_vector_type(4)));
typedef float f32x4 __attribute__((ext_vector_type(4)));

// ---------------- edge prep: last-write-wins scatter index + dst histogram ----------------
__global__ __launch_bounds__(256) void k_edge_prep(const int* __restrict__ ei,
                                                   int* __restrict__ le, int* __restrict__ deg) {
  int e = blockIdx.x * 256 + threadIdx.x;
  if (e < NE) {
    atomicMax(&le[ei[e]], e);        // src: last edge index wins
    atomicAdd(&deg[ei[NE + e]], 1);  // dst degree
  }
}

// eembz: [R+1][IND], rows 0..5 = eemb, row 6 = zeros (branchless "no edge" row)
__global__ __launch_bounds__(256) void k_eembz(const float* __restrict__ eemb,
                                               float* __restrict__ ez) {
  int i = blockIdx.x * 256 + threadIdx.x;
  if (i < 7 * IND) ez[i] = (i < 6 * IND) ? eemb[i] : 0.f;
}

// ---------------- A1 = bf16(x + eembz[et[le[row]]]) : pure streaming prepass ----------------
__global__ __launch_bounds__(256) void k_prep_a(const float* __restrict__ x,
                                                const int* __restrict__ le,
                                                const int* __restrict__ et,
                                                const float* __restrict__ eembz,
                                                bf16* __restrict__ A1) {
  int idx = blockIdx.x * 256 + threadIdx.x;  // one thread = 8 elements
  if (idx >= NN * (IND / 8)) return;
  int row = idx / (IND / 8);
  int c = (idx - row * (IND / 8)) * 8;
  int l = le[row];
  int e = (l >= 0) ? et[l] : 6;  // row 6 of eembz is zeros
  const float* px = x + (size_t)row * IND + c;
  const float* pe = eembz + (size_t)e * IND + c;
  float4 v0 = *(const float4*)px, v1 = *(const float4*)(px + 4);
  float4 e0 = *(const float4*)pe, e1 = *(const float4*)(pe + 4);
  bf16x8 o;
  o[0] = (bf16)(v0.x + e0.x); o[1] = (bf16)(v0.y + e0.y);
  o[2] = (bf16)(v0.z + e0.z); o[3] = (bf16)(v0.w + e0.w);
  o[4] = (bf16)(v1.x + e1.x); o[5] = (bf16)(v1.y + e1.y);
  o[6] = (bf16)(v1.z + e1.z); o[7] = (bf16)(v1.w + e1.w);
  *(bf16x8*)(A1 + (size_t)row * IND + c) = o;
}

// ---------------- CSR build: scan + scatter ----------------
__global__ __launch_bounds__(256) void k_scan_block(const int* __restrict__ deg,
                                                    int* __restrict__ excl, int* __restrict__ bsum) {
  __shared__ int sm[256];
  int tid = threadIdx.x;
  int i = blockIdx.x * 256 + tid;
  int v = (i < NN) ? deg[i] : 0;
  sm[tid] = v;
  __syncthreads();
#pragma unroll
  for (int off = 1; off < 256; off <<= 1) {
    int t = (tid >= off) ? sm[tid - off] : 0;
    __syncthreads();
    sm[tid] += t;
    __syncthreads();
  }
  if (i < NN) excl[i] = sm[tid] - v;
  if (tid == 255) bsum[blockIdx.x] = sm[255];
}

__global__ __launch_bounds__(256) void k_scan_partials(const int* __restrict__ bsum,
                                                       int* __restrict__ bbase) {
  __shared__ int sm[256];
  int tid = threadIdx.x;
  int v = (tid < NB) ? bsum[tid] : 0;
  sm[tid] = v;
  __syncthreads();
#pragma unroll
  for (int off = 1; off < 256; off <<= 1) {
    int t = (tid >= off) ? sm[tid - off] : 0;
    __syncthreads();
    sm[tid] += t;
    __syncthreads();
  }
  bbase[tid] = sm[tid] - v;
}

__global__ __launch_bounds__(256) void k_add_base(const int* __restrict__ excl,
                                                  const int* __restrict__ bbase,
                                                  int* __restrict__ rowstart, int* __restrict__ cur) {
  int i = blockIdx.x * 256 + threadIdx.x;
  if (i < NN) {
    int rs = excl[i] + bbase[i >> 8];
    rowstart[i] = rs;
    cur[i] = rs;
  }
}

__global__ __launch_bounds__(256) void k_scatter_csr(const int* __restrict__ ei,
                                                     int* __restrict__ cur, int* __restrict__ csr) {
  int e = blockIdx.x * 256 + threadIdx.x;
  if (e < NE) {
    int d = ei[NE + e];
    int pos = atomicAdd(&cur[d], 1);
    csr[pos] = ei[e];  // store src node id
  }
}

// W [K, NC] fp32 -> Wt [NC, K] bf16
__global__ __launch_bounds__(256) void k_transpose(const float* __restrict__ W,
                                                   bf16* __restrict__ Wt, int K, int NC) {
  int k = blockIdx.x * 256 + threadIdx.x;
  int n = blockIdx.y;
  if (k < K) Wt[n * K + k] = (bf16)W[k * NC + n];
}

__device__ __forceinline__ void gld16(const bf16* g, bf16* l) {
  __builtin_amdgcn_global_load_lds((const __attribute__((address_space(1))) void*)g,
                                   (__attribute__((address_space(3))) void*)l, 16, 0, 0);
}

// ---------------- MFMA GEMM: C[M,NC] = A[M,K] * Bt[NC,K]^T ----------------
// 128xTN tile, BK=32, 4 waves. TN=128: 2x2 waves, 64x64/wave (4x4 frags).
// TN=64: 4x1 waves, 32x64/wave (2x4 frags) — no wasted MFMA when NC=64.
// Depth-2 pipelined double-buffer (T3/T4 minimum form): counted vmcnt
// (never 0 in steady state) + raw s_barrier; restage consumed buffer for
// t+2 after an lgkmcnt(0)-guarded WAR barrier. HBM latency of tile t+2
// hides under compute of tiles t, t+1.
// Epilogue emits attention logits alS/alD (per-row dot with aS/aD).
template <typename OutT, int TN>
__global__ __launch_bounds__(256) void k_gemm_bt(const bf16* __restrict__ A,
                                                 const bf16* __restrict__ Bt,
                                                 OutT* __restrict__ C,
                                                 int M, int K, int NC,
                                                 const float* __restrict__ aS,
                                                 const float* __restrict__ aD,
                                                 float* __restrict__ alS,
                                                 float* __restrict__ alD,
                                                 int alStride) {
  constexpr int MI = (TN == 128) ? 4 : 2;  // 16-row frags per wave
  constexpr int WROWS = MI * 16;           // rows per wave
  __shared__ bf16 As[2][128 * 32];
  __shared__ bf16 Bs[2][TN * 32];
  const int tid = threadIdx.x;
  const int lane = tid & 63;
  const int wave = tid >> 6;
  const int wr = (TN == 128) ? (wave >> 1) : wave;
  const int wc = (TN == 128) ? (wave & 1) : 0;
  const int ln15 = lane & 15, q = lane >> 4;
  const int n0 = blockIdx.x * TN;  // n fastest-varying: adjacent blocks share A-tile
  const int m0 = blockIdx.y * 128;

  // staging geometry: one gld16 call = 64 lanes x 16B = 1KB = 16 rows of [32] bf16.
  // lane l -> row +(l>>2), 16B chunk (l&3). LDS dest is wave-uniform base (linear).
  const int sr = lane >> 2;
  const int scol = (lane & 3) * 8;  // bf16 elements
  const int gA0 = min(m0 + wave * 32 + sr, M - 1);
  const int gA1 = min(m0 + wave * 32 + 16 + sr, M - 1);
  int gB0, gB1 = 0;
  if constexpr (TN == 128) {
    gB0 = min(n0 + wave * 32 + sr, NC - 1);
    gB1 = min(n0 + wave * 32 + 16 + sr, NC - 1);
  } else {
    gB0 = min(n0 + wave * 16 + sr, NC - 1);
  }

  auto stage = [&](int buf, int kt) {
    gld16(A + (size_t)gA0 * K + kt + scol, &As[buf][(wave * 32) * 32]);
    gld16(A + (size_t)gA1 * K + kt + scol, &As[buf][(wave * 32 + 16) * 32]);
    if constexpr (TN == 128) {
      gld16(Bt + (size_t)gB0 * K + kt + scol, &Bs[buf][(wave * 32) * 32]);
      gld16(Bt + (size_t)gB1 * K + kt + scol, &Bs[buf][(wave * 32 + 16) * 32]);
    } else {
      gld16(Bt + (size_t)gB0 * K + kt + scol, &Bs[buf][(wave * 16) * 32]);
    }
  };

  f32x4 acc[MI][4] = {};

  auto compute = [&](int buf) {
    bf16x8 af[MI], bfr[4];
#pragma unroll
    for (int i = 0; i < MI; i++)
      af[i] = *(const bf16x8*)(&As[buf][(wr * WROWS + i * 16 + ln15) * 32 + q * 8]);
#pragma unroll
    for (int i = 0; i < 4; i++)
      bfr[i] = *(const bf16x8*)(&Bs[buf][(wc * 64 + i * 16 + ln15) * 32 + q * 8]);
#pragma unroll
    for (int mi = 0; mi < MI; mi++)
#pragma unroll
      for (int ni = 0; ni < 4; ni++)
        acc[mi][ni] = __builtin_amdgcn_mfma_f32_16x16x32_bf16(af[mi], bfr[ni], acc[mi][ni], 0, 0, 0);
  };

  const int NT = K >> 5;

  // prologue: two tiles in flight
  stage(0, 0);
  stage(1, 32);
  int cur = 0;
  for (int t = 0; t < NT; ++t) {
    // wait for buf[cur]'s stage to land (counted: newer stage stays in flight)
    if (t < NT - 1) {
      if constexpr (TN == 128) asm volatile("s_waitcnt vmcnt(4)" ::: "memory");
      else                     asm volatile("s_waitcnt vmcnt(3)" ::: "memory");
    } else {
      asm volatile("s_waitcnt vmcnt(0)" ::: "memory");
    }
    __builtin_amdgcn_s_barrier();  // RAW: buf[cur] published to all waves
    compute(cur);
    if (t + 2 < NT) {
      // WAR: all waves' ds_reads of buf[cur] complete before overwrite
      asm volatile("s_waitcnt lgkmcnt(0)" ::: "memory");
      __builtin_amdgcn_s_barrier();
      stage(cur, (t + 2) << 5);
    }
    cur ^= 1;
  }

  // epilogue 1: C store. C/D layout col=lane&15, row=(lane>>4)*4+reg
#pragma unroll
  for (int mi = 0; mi < MI; mi++)
#pragma unroll
    for (int ni = 0; ni < 4; ni++)
#pragma unroll
      for (int r = 0; r < 4; r++) {
        int row = m0 + wr * WROWS + mi * 16 + q * 4 + r;
        int col = n0 + wc * 64 + ni * 16 + ln15;
        if (row < M && col < NC) C[(size_t)row * NC + col] = (OutT)acc[mi][ni][r];
      }

  // epilogue 2: attention logits. Each wave's 64-col slice == one head slice;
  // each (row, hd) produced by exactly one wave grid-wide -> plain stores.
  if (n0 + wc * 64 < NC) {
    const int hd = (n0 + wc * 64) >> 6;
#pragma unroll
    for (int mi = 0; mi < MI; mi++)
#pragma unroll
      for (int r = 0; r < 4; r++) {
        float ps = 0.f, pd = 0.f;
#pragma unroll
        for (int ni = 0; ni < 4; ni++) {
          int col = n0 + wc * 64 + ni * 16 + ln15;
          float w_s = (col < NC) ? aS[col] : 0.f;
          float w_d = (col < NC) ? aD[col] : 0.f;
          ps += acc[mi][ni][r] * w_s;
          pd += acc[mi][ni][r] * w_d;
        }
#pragma unroll
        for (int off = 1; off < 16; off <<= 1) {
          ps += __shfl_xor(ps, off);
          pd += __shfl_xor(pd, off);
        }
        int row = m0 + wr * WROWS + mi * 16 + q * 4 + r;
        if (ln15 == 0 && row < M) {
          alS[row * alStride + hd] = ps;
          alD[row * alStride + hd] = pd;
        }
      }
  }
}

// ---------------- fused gather-aggregate + LN + ELU, layer 1 ----------------
// 1 wave = 1 node (64 lanes x 4 feats, bf16x4 = 8B/lane gather loads);
// LN reduction is a pure wave shuffle — no LDS, no __syncthreads.
__global__ __launch_bounds__(256) void k_agg_ln1(const int* __restrict__ rowstart,
                                                 const int* __restrict__ deg,
                                                 const int* __restrict__ csr,
                                                 const bf16* __restrict__ h1,
                                                 const float* __restrict__ alS,
                                                 const float* __restrict__ alD,
                                                 const float* __restrict__ b1,
                                                 const float* __restrict__ g1,
                                                 const float* __restrict__ be1,
                                                 bf16* __restrict__ hln) {
  const int n = blockIdx.x * 4 + (threadIdx.x >> 6);  // 50000 % 4 == 0
  const int lane = threadIdx.x & 63;
  const int f0 = lane * 4;       // 4 consecutive feats, same head (4 | 64)
  const int hd = lane >> 4;
  int start = rowstart[n], cnt = deg[n];
  float ald = alD[n * 4 + hd];
  float accv0 = 0.f, accv1 = 0.f, accv2 = 0.f, accv3 = 0.f, accw = 0.f;
  for (int j = 0; j < cnt; j++) {
    int s = csr[start + j];
    float logit = alS[s * 4 + hd] + ald;
    logit = logit >= 0.f ? logit : 0.2f * logit;
    float w = __expf(logit);  // shift-free softmax: logits bounded by construction
    bf16x4 hv = *(const bf16x4*)(h1 + (size_t)s * HID + f0);
    accv0 += w * (float)hv[0];
    accv1 += w * (float)hv[1];
    accv2 += w * (float)hv[2];
    accv3 += w * (float)hv[3];
    accw += w;
  }
  float inv = (cnt > 0) ? 1.f / accw : 0.f;
  float4 bv = *(const float4*)(b1 + f0);
  float v0 = accv0 * inv + bv.x;
  float v1 = accv1 * inv + bv.y;
  float v2 = accv2 * inv + bv.z;
  float v3 = accv3 * inv + bv.w;
  float s = v0 + v1 + v2 + v3;
  float ss = v0 * v0 + v1 * v1 + v2 * v2 + v3 * v3;
#pragma unroll
  for (int off = 32; off; off >>= 1) { s += __shfl_xor(s, off); ss += __shfl_xor(ss, off); }
  float mu = s * (1.f / HID);
  float var = ss * (1.f / HID) - mu * mu;
  float rs = rsqrtf(var + 1e-5f);
  float4 gv = *(const float4*)(g1 + f0);
  float4 ev = *(const float4*)(be1 + f0);
  float y0 = (v0 - mu) * rs * gv.x + ev.x;
  float y1 = (v1 - mu) * rs * gv.y + ev.y;
  float y2 = (v2 - mu) * rs * gv.z + ev.z;
  float y3 = (v3 - mu) * rs * gv.w + ev.w;
  y0 = y0 > 0.f ? y0 : __expf(y0) - 1.f;  // ELU
  y1 = y1 > 0.f ? y1 : __expf(y1) - 1.f;
  y2 = y2 > 0.f ? y2 : __expf(y2) - 1.f;
  y3 = y3 > 0.f ? y3 : __expf(y3) - 1.f;
  bf16x4 o;
  o[0] = (bf16)y0; o[1] = (bf16)y1; o[2] = (bf16)y2; o[3] = (bf16)y3;
  *(bf16x4*)(hln + (size_t)n * HID + f0) = o;
}

// ---------------- fused gather-aggregate + LN, layer 2 ----------------
// 1 wave = 1 node (64 lanes x 1 fp32 feat); wave-shuffle LN.
__global__ __launch_bounds__(256) void k_agg_ln2(const int* __restrict__ rowstart,
                                                 const int* __restrict__ deg,
                                                 const int* __restrict__ csr,
                                                 const float* __restrict__ h2,
                                                 const float* __restrict__ alS,
                                                 const float* __restrict__ alD,
                                                 const float* __restrict__ b2,
                                                 const float* __restrict__ g2,
                                                 const float* __restrict__ be2,
                                                 float* __restrict__ out) {
  const int n = blockIdx.x * 4 + (threadIdx.x >> 6);
  const int f = threadIdx.x & 63;
  int start = rowstart[n], cnt = deg[n];
  float ald = alD[n];
  float accv = 0.f, accw = 0.f;
  for (int j = 0; j < cnt; j++) {
    int s = csr[start + j];
    float logit = alS[s] + ald;
    logit = logit >= 0.f ? logit : 0.2f * logit;
    float w = __expf(logit);
    accv += w * h2[(size_t)s * OUTD + f];
    accw += w;
  }
  float v = (cnt > 0) ? accv / accw : 0.f;
  v += b2[f];
  float s = v, ss = v * v;
#pragma unroll
  for (int off = 32; off; off >>= 1) { s += __shfl_xor(s, off); ss += __shfl_xor(ss, off); }
  float mu = s * (1.f / OUTD);
  float var = ss * (1.f / OUTD) - mu * mu;
  out[(size_t)n * OUTD + f] = (v - mu) * rsqrtf(var + 1e-5f) * g2[f] + be2[f];
}

extern "C" void kernel_launch(void* const* d_in, const int* in_sizes, int n_in,
                              void* d_out, int out_size, void* d_ws, size_t ws_size,
                              hipStream_t stream) {
  const float* x    = (const float*)d_in[0];
  const int*   ei   = (const int*)d_in[1];
  const int*   et   = (const int*)d_in[2];
  const float* eemb = (const float*)d_in[3];
  const float* W1   = (const float*)d_in[4];
  const float* as1  = (const float*)d_in[5];
  const float* ad1  = (const float*)d_in[6];
  const float* b1   = (const float*)d_in[7];
  const float* g1   = (const float*)d_in[8];
  const float* be1  = (const float*)d_in[9];
  const float* W2   = (const float*)d_in[10];
  const float* as2  = (const float*)d_in[11];
  const float* ad2  = (const float*)d_in[12];
  const float* b2   = (const float*)d_in[13];
  const float* g2   = (const float*)d_in[14];
  const float* be2  = (const float*)d_in[15];
  float* out = (float*)d_out;

  char* base = (char*)d_ws;
  size_t off = 0;
  auto alloc = [&](size_t bytes) -> void* {
    void* p = base + off;
    off = (off + bytes + 255) & ~(size_t)255;
    return p;
  };
  int*   le    = (int*)alloc((size_t)NN * 4);
  int*   deg   = (int*)alloc((size_t)NN * 4);
  int*   excl  = (int*)alloc((size_t)NN * 4);
  int*   bsum  = (int*)alloc(256 * 4);
  int*   bbase = (int*)alloc(256 * 4);
  int*   rowst = (int*)alloc((size_t)NN * 4);
  int*   cur   = (int*)alloc((size_t)NN * 4);
  int*   csr   = (int*)alloc((size_t)NE * 4);
  bf16*  h1    = (bf16*)alloc((size_t)NN * HID * 2);
  float* alS1  = (float*)alloc((size_t)NN * 4 * 4);
  float* alD1  = (float*)alloc((size_t)NN * 4 * 4);
  bf16*  W1t   = (bf16*)alloc((size_t)HID * IND * 2);
  bf16*  W2t   = (bf16*)alloc((size_t)OUTD * HID * 2);
  float* eembz = (float*)alloc((size_t)7 * IND * 4);
  // region R: A1 (live prep_a..gemm1) aliased by {hln, h2, alS2, alD2} (live after gemm1)
  char*  R     = (char*)alloc((size_t)NN * IND * 2);
  bf16*  A1    = (bf16*)R;
  bf16*  hln   = (bf16*)R;
  float* h2    = (float*)(R + (size_t)NN * HID * 2);
  float* alS2  = (float*)(R + (size_t)NN * HID * 2 + (size_t)NN * OUTD * 4);
  float* alD2  = (float*)(R + (size_t)NN * HID * 2 + (size_t)NN * OUTD * 4 + (size_t)NN * 4);

  hipMemsetAsync(le, 0xFF, (size_t)NN * 4, stream);  // -1
  hipMemsetAsync(deg, 0, (size_t)NN * 4, stream);

  // CSR build + last-edge index + zero-padded edge-emb table
  k_edge_prep<<<(NE + 255) / 256, 256, 0, stream>>>(ei, le, deg);
  k_eembz<<<(7 * IND + 255) / 256, 256, 0, stream>>>(eemb, eembz);
  // streaming prepass: A1 = bf16(x + edge_emb)
  k_prep_a<<<(NN * (IND / 8) + 255) / 256, 256, 0, stream>>>(x, le, et, eembz, A1);
  k_scan_block<<<NB, 256, 0, stream>>>(deg, excl, bsum);
  k_scan_partials<<<1, 256, 0, stream>>>(bsum, bbase);
  k_add_base<<<NB, 256, 0, stream>>>(excl, bbase, rowst, cur);
  k_scatter_csr<<<(NE + 255) / 256, 256, 0, stream>>>(ei, cur, csr);

  // weights
  k_transpose<<<dim3(3, HID), 256, 0, stream>>>(W1, W1t, IND, HID);
  k_transpose<<<dim3(1, OUTD), 256, 0, stream>>>(W2, W2t, HID, OUTD);

  // layer 1: clean bf16 GEMM (pipelined) -> h1 + logits
  k_gemm_bt<bf16, 128><<<dim3(2, (NN + 127) / 128), 256, 0, stream>>>(
      A1, W1t, h1, NN, IND, HID, as1, ad1, alS1, alD1, 4);
  k_agg_ln1<<<NN / 4, 256, 0, stream>>>(rowst, deg, csr, h1, alS1, alD1, b1, g1, be1, hln);

  // layer 2: narrow GEMM (TN=64, no wasted MFMA) -> h2 + logits
  k_gemm_bt<float, 64><<<dim3(1, (NN + 127) / 128), 256, 0, stream>>>(
      hln, W2t, h2, NN, HID, OUTD, as2, ad2, alS2, alD2, 1);
  k_agg_ln2<<<NN / 4, 256, 0, stream>>>(rowst, deg, csr, h2, alS2, alD2, b2, g2, be2, out);
}